// Round 11
// baseline (392.301 us; speedup 1.0000x reference)
//
#include <hip/hip_runtime.h>
#include <hip/hip_fp16.h>

// GCN 2-hop propagation, CSR-gather formulation, fp16 intermediates,
// chunk-ordered adjacency for L2-resident gathers.
// Inputs: edge_index (2,E) int32; x (N,128) f32; W (128,64) f32. Output (N,64) f32.
//
// Math: deg[r] = #(non-self edges from r) + 1; dis = rsqrt(deg); selfn = 1/deg.
//   g  = dis * (x@W)                  (stored fp16)
//   g1[r]  = selfn[r] * (g[r]  + sum_{r->c} g[c])    (= dis*y1, stored fp16)
//   out[r] = dis[r]   * (g1[r] + sum_{r->c} g1[c])   (f32)
//
// colidx within each row is grouped by source CHUNK (16384 rows = 2MB of g,
// fits each XCD's 4MB L2). SPMM sweeps chunks in an outer loop with
// register-resident row accumulators; all blocks co-resident -> chip-wide
// the active gather slice stays L2-hot.

#define RPB 1024        // rows per sort bucket
#define RPB_SHIFT 10
#define CBITS 17        // bits for col index (N < 131072)
#define CMASK ((1 << CBITS) - 1)
#define CH_SHIFT 14     // 16384 rows per chunk
#define NCH_MAX 8       // slots per row in cs8 (7 chunks + end sentinel)
#define P1_TPB 1024
#define P1_EPT 8
#define P1_CHUNK (P1_TPB * P1_EPT)  // 8192 edges per block
#define MAXNB 128       // max sort buckets (N <= 131072)
#define BCAP 36864      // bucket capacity; E/nb = 32653, sigma ~180 -> 23 sigma
#define SROWS 16        // rows per wave in SPMM

// bcur[b] = b*BCAP (start of bucket b's fixed region)
__global__ __launch_bounds__(128) void k_init_bcur(int* __restrict__ bcur, int nb) {
  int b = blockIdx.x * 128 + threadIdx.x;
  if (b < nb) bcur[b] = b * BCAP;
}

// Sort pass 1: 8192 edges/block in registers, LDS histogram over coarse
// buckets, ONE global atomic per (block,bucket), contiguous packed writes.
__global__ __launch_bounds__(P1_TPB) void k_part1(const int* __restrict__ rows,
                                                  const int* __restrict__ cols,
                                                  int* __restrict__ bcur,
                                                  int* __restrict__ pairs,
                                                  int E, int nb) {
  __shared__ int hist[MAXNB];
  __shared__ int goff[MAXNB];
  int tid = threadIdx.x;
  long base = (long)blockIdx.x * P1_CHUNK;
  int r[P1_EPT], c[P1_EPT];
#pragma unroll
  for (int i = 0; i < P1_EPT; ++i) {
    long e = base + (long)i * P1_TPB + tid;
    if (e < E) {
      r[i] = rows[e];
      c[i] = cols[e];
    } else {
      r[i] = -1;
      c[i] = -1;  // r==c -> skipped
    }
  }
  if (tid < nb) hist[tid] = 0;
  __syncthreads();
#pragma unroll
  for (int i = 0; i < P1_EPT; ++i)
    if (r[i] != c[i]) atomicAdd(&hist[r[i] >> RPB_SHIFT], 1);
  __syncthreads();
  if (tid < nb) {
    int h = hist[tid];
    goff[tid] = h ? atomicAdd(&bcur[tid], h) : 0;
    hist[tid] = 0;  // reuse as local rank cursor
  }
  __syncthreads();
#pragma unroll
  for (int i = 0; i < P1_EPT; ++i) {
    if (r[i] != c[i]) {
      int b = r[i] >> RPB_SHIFT;
      int rank = atomicAdd(&hist[b], 1);
      pairs[goff[b] + rank] = ((r[i] & (RPB - 1)) << CBITS) | c[i];
    }
  }
}

// Sort pass 2: one block per bucket. Per-(row,chunk) LDS histogram ->
// norms + per-row chunk-segment offsets cs8[row][0..7] (slot 7 = row end),
// then chunk-grouped scatter of colidx within the bucket's window.
__global__ __launch_bounds__(P1_TPB) void k_part3(const int* __restrict__ bcur,
                                                  const int* __restrict__ pairs,
                                                  int* __restrict__ colidx,
                                                  int* __restrict__ cs8,
                                                  float* __restrict__ dis,
                                                  float* __restrict__ selfn, int n) {
  __shared__ int cnt[RPB * NCH_MAX];  // 32 KB: per-(row,chunk) counts/cursors
  __shared__ int lscan[RPB];
  int tid = threadIdx.x;
  int b = blockIdx.x;
  int base = b * RPB;
  int e0 = b * BCAP;
  int e1 = bcur[b];
  for (int j = tid; j < RPB * NCH_MAX; j += P1_TPB) cnt[j] = 0;
  __syncthreads();
  for (int i = e0 + tid; i < e1; i += P1_TPB) {
    int v = pairs[i];
    int lr = v >> CBITS;
    int ch = (v & CMASK) >> CH_SHIFT;
    atomicAdd(&cnt[lr * NCH_MAX + ch], 1);
  }
  __syncthreads();
  int cc[NCH_MAX - 1];
  int d = 0;
#pragma unroll
  for (int j = 0; j < NCH_MAX - 1; ++j) {
    cc[j] = cnt[tid * NCH_MAX + j];
    d += cc[j];
  }
  int row = base + tid;
  if (row < n) {
    float dd = (float)d + 1.0f;
    dis[row] = rsqrtf(dd);
    selfn[row] = 1.0f / dd;
  }
  // inclusive scan of row degrees
  lscan[tid] = d;
  __syncthreads();
  for (int off = 1; off < RPB; off <<= 1) {
    int t = (tid >= off) ? lscan[tid - off] : 0;
    __syncthreads();
    lscan[tid] += t;
    __syncthreads();
  }
  int rstart = e0 + lscan[tid] - d;  // exclusive, within bucket window
  // per-row chunk offsets
  int cs[NCH_MAX];
  cs[0] = rstart;
#pragma unroll
  for (int j = 0; j < NCH_MAX - 1; ++j) cs[j + 1] = cs[j] + cc[j];
  if (row < n) {
    *(int4*)&cs8[(size_t)row * NCH_MAX] = make_int4(cs[0], cs[1], cs[2], cs[3]);
    *(int4*)&cs8[(size_t)row * NCH_MAX + 4] = make_int4(cs[4], cs[5], cs[6], cs[7]);
  }
#pragma unroll
  for (int j = 0; j < NCH_MAX - 1; ++j) cnt[tid * NCH_MAX + j] = cs[j];  // cursors
  __syncthreads();
  for (int i = e0 + tid; i < e1; i += P1_TPB) {
    int v = pairs[i];
    int lr = v >> CBITS;
    int c = v & CMASK;
    int p = atomicAdd(&cnt[lr * NCH_MAX + (c >> CH_SHIFT)], 1);
    colidx[p] = c;
  }
}

// g = dis * (x @ W) stored fp16.
// x tile (32x128 f32 = 16KB) staged in LDS via lane-distributed coalesced
// float4 loads; inner loop reads x as LDS b128 broadcasts, W in registers.
#define GR 32  // rows per block
__global__ __launch_bounds__(256) void k_gemm_scale(const float* __restrict__ x,
                                                    const float* __restrict__ W,
                                                    const float* __restrict__ dis,
                                                    __half* __restrict__ g, int n) {
  __shared__ __align__(16) float xs[GR * 128];  // 16 KB
  int tid = threadIdx.x;
  int f = tid & 63;
  int wid = tid >> 6;
  int row0 = blockIdx.x * GR;
  {
    const float4* xg = (const float4*)(x + (size_t)row0 * 128);
    float4* xs4 = (float4*)xs;
    if (row0 + GR <= n) {
#pragma unroll
      for (int i = 0; i < 4; ++i) xs4[tid + i * 256] = xg[tid + i * 256];
    } else {
      int nf4 = (n - row0) * 32;
      for (int i = tid; i < nf4; i += 256) xs4[i] = xg[i];
    }
  }
  __syncthreads();
  float acc[8] = {0.f, 0.f, 0.f, 0.f, 0.f, 0.f, 0.f, 0.f};
  const float* xw = xs + (wid * 8) * 128;
  for (int kc = 0; kc < 128; kc += 32) {
    float w[32];
#pragma unroll
    for (int j = 0; j < 32; ++j) w[j] = W[(kc + j) * 64 + f];  // coalesced, L2-hit
#pragma unroll
    for (int rr = 0; rr < 8; ++rr) {
      const float* xr = xw + rr * 128 + kc;
#pragma unroll
      for (int j = 0; j < 32; j += 4) {
        float4 xv = *reinterpret_cast<const float4*>(xr + j);  // LDS broadcast
        acc[rr] += xv.x * w[j] + xv.y * w[j + 1] + xv.z * w[j + 2] + xv.w * w[j + 3];
      }
    }
  }
  int rbase = row0 + wid * 8;
#pragma unroll
  for (int rr = 0; rr < 8; ++rr) {
    int row = rbase + rr;
    if (row < n) g[(size_t)row * 64 + f] = __float2half_rn(dis[row] * acc[rr]);
  }
}

// Chunked SPMM: wave owns SROWS=16 rows (acc in registers, 2 rows per
// half-wave pair x 8 slots). Outer loop over source chunks keeps the 2MB
// gather slice L2-resident chip-wide (all blocks co-resident & balanced).
template <bool OUTF32>
__global__ __launch_bounds__(256) void k_spmm_c(const int* __restrict__ cs8,
                                                const int* __restrict__ colidx,
                                                const float* __restrict__ scale,
                                                const __half* __restrict__ gin,
                                                void* __restrict__ gout,
                                                int n, int nch) {
  int tid = threadIdx.x;
  int lane = tid & 63;
  int wid = tid >> 6;
  int half = lane >> 5;
  int f2 = lane & 31;
  int base = (blockIdx.x * 4 + wid) * SROWS;
  if (base >= n) return;
  const __half2* gin2 = (const __half2*)gin;
  float ax[8], ay[8];
#pragma unroll
  for (int s = 0; s < 8; ++s) {
    int r = base + 2 * s + half;
    if (r < n) {
      float2 v = __half22float2(gin2[(size_t)r * 32 + f2]);  // self loop
      ax[s] = v.x;
      ay[s] = v.y;
    } else {
      ax[s] = 0.f;
      ay[s] = 0.f;
    }
  }
  for (int ch = 0; ch < nch; ++ch) {
#pragma unroll
    for (int s = 0; s < 8; ++s) {
      int r = base + 2 * s + half;
      if (r >= n) continue;
      int j = cs8[(size_t)r * NCH_MAX + ch];
      int jend = cs8[(size_t)r * NCH_MAX + ch + 1];
      for (; j + 4 <= jend; j += 4) {
        int c0 = colidx[j + 0];
        int c1 = colidx[j + 1];
        int c2 = colidx[j + 2];
        int c3 = colidx[j + 3];
        float2 v0 = __half22float2(gin2[(size_t)c0 * 32 + f2]);
        float2 v1 = __half22float2(gin2[(size_t)c1 * 32 + f2]);
        float2 v2 = __half22float2(gin2[(size_t)c2 * 32 + f2]);
        float2 v3 = __half22float2(gin2[(size_t)c3 * 32 + f2]);
        ax[s] += v0.x + v1.x + v2.x + v3.x;
        ay[s] += v0.y + v1.y + v2.y + v3.y;
      }
      for (; j < jend; ++j) {
        int c = colidx[j];
        float2 v = __half22float2(gin2[(size_t)c * 32 + f2]);
        ax[s] += v.x;
        ay[s] += v.y;
      }
    }
  }
#pragma unroll
  for (int s = 0; s < 8; ++s) {
    int r = base + 2 * s + half;
    if (r < n) {
      float sc = scale[r];
      if (OUTF32) {
        ((float2*)gout)[(size_t)r * 32 + f2] = make_float2(sc * ax[s], sc * ay[s]);
      } else {
        ((__half2*)gout)[(size_t)r * 32 + f2] = __floats2half2_rn(sc * ax[s], sc * ay[s]);
      }
    }
  }
}

extern "C" void kernel_launch(void* const* d_in, const int* in_sizes, int n_in,
                              void* d_out, int out_size, void* d_ws, size_t ws_size,
                              hipStream_t stream) {
  const int* edge = (const int*)d_in[0];
  const float* x = (const float*)d_in[1];
  const float* W = (const float*)d_in[2];
  float* out = (float*)d_out;

  int E = in_sizes[0] / 2;
  int N = in_sizes[1] / 128;
  const int* rows = edge;      // edge_index[0]
  const int* cols = edge + E;  // edge_index[1]
  int nbuckets = (N + RPB - 1) / RPB;       // 98 for N=100000
  int nch = ((N - 1) >> CH_SHIFT) + 1;      // 7 for N=100000

  char* p = (char*)d_ws;
  auto alloc = [&](size_t bytes) {
    char* q = p;
    p += (bytes + 255) & ~(size_t)255;
    return q;
  };
  size_t slots = (size_t)nbuckets * BCAP;
  int* cs8       = (int*)alloc((size_t)N * NCH_MAX * 4);  // 3.2 MB
  int* bcur      = (int*)alloc((size_t)nbuckets * 4);
  int* colidx    = (int*)alloc(slots * 4);
  float* dis     = (float*)alloc((size_t)N * 4);
  float* selfn   = (float*)alloc((size_t)N * 4);
  __half* g      = (__half*)alloc((size_t)N * 64 * 2);
  size_t g1_bytes = (size_t)N * 64 * 2;
  size_t pairs_bytes = slots * 4;
  char* g1_raw = (char*)alloc(g1_bytes > pairs_bytes ? g1_bytes : pairs_bytes);
  __half* g1 = (__half*)g1_raw;  // hop-1 output
  int* pairs = (int*)g1_raw;     // aliased: dead before g1 is written

  int p1_blocks = (int)(((long)E + P1_CHUNK - 1) / P1_CHUNK);
  int spmm_blocks = (N + 4 * SROWS - 1) / (4 * SROWS);

  // --- bucketed counting sort (fixed-capacity regions, chunk-grouped) ---
  k_init_bcur<<<(nbuckets + 127) / 128, 128, 0, stream>>>(bcur, nbuckets);
  k_part1<<<p1_blocks, P1_TPB, 0, stream>>>(rows, cols, bcur, pairs, E, nbuckets);
  k_part3<<<nbuckets, P1_TPB, 0, stream>>>(bcur, pairs, colidx, cs8, dis, selfn, N);

  // --- feature transform (pre-scaled, fp16 out) ---
  k_gemm_scale<<<(N + GR - 1) / GR, 256, 0, stream>>>(x, W, dis, g, N);

  // --- hop 1: g1 = selfn * (g_self + gather)  [fp16] ---
  k_spmm_c<false><<<spmm_blocks, 256, 0, stream>>>(cs8, colidx, selfn, g,
                                                   (void*)g1, N, nch);

  // --- hop 2: out = dis * (g1_self + gather)  [f32] ---
  k_spmm_c<true><<<spmm_blocks, 256, 0, stream>>>(cs8, colidx, dis, g1,
                                                  (void*)out, N, nch);
}

// Round 12
// 230.817 us; speedup vs baseline: 1.6996x; 1.6996x over previous
//
#include <hip/hip_runtime.h>
#include <hip/hip_fp16.h>

// GCN 2-hop propagation, CSR-gather formulation, fp16 intermediates.
// Sort = fixed-capacity bucketed counting sort (no histogram pre-pass,
// no random global atomics). Inputs: edge_index (2,E) int32; x (N,128) f32;
// W (128,64) f32. Output (N,64) f32.
//
// Math: deg[r] = #(non-self edges from r) + 1; dis = rsqrt(deg); selfn = 1/deg.
//   g  = dis * (x@W)                  (stored fp16)
//   g1[r]  = selfn[r] * (g[r]  + sum_{r->c} g[c])    (= dis*y1, stored fp16)
//   out[r] = dis[r]   * (g1[r] + sum_{r->c} g1[c])   (f32)

#define RPB 1024        // rows per bucket
#define RPB_SHIFT 10
#define CBITS 17        // bits for col index (N < 131072)
#define CMASK ((1 << CBITS) - 1)
#define P1_TPB 1024
#define P1_EPT 8
#define P1_CHUNK (P1_TPB * P1_EPT)  // 8192 edges per block
#define MAXNB 128       // max buckets (N <= 131072)
#define BCAP 36864      // bucket capacity; E/nb = 32653, sigma ~180 -> 23 sigma

// bcur[b] = b*BCAP (start of bucket b's fixed region)
__global__ __launch_bounds__(128) void k_init_bcur(int* __restrict__ bcur, int nb) {
  int b = blockIdx.x * 128 + threadIdx.x;
  if (b < nb) bcur[b] = b * BCAP;
}

// Sort pass 1: 8192 edges/block in registers, LDS histogram over coarse
// buckets, ONE global atomic per (block,bucket), contiguous packed writes.
__global__ __launch_bounds__(P1_TPB) void k_part1(const int* __restrict__ rows,
                                                  const int* __restrict__ cols,
                                                  int* __restrict__ bcur,
                                                  int* __restrict__ pairs,
                                                  int E, int nb) {
  __shared__ int hist[MAXNB];
  __shared__ int goff[MAXNB];
  int tid = threadIdx.x;
  long base = (long)blockIdx.x * P1_CHUNK;
  int r[P1_EPT], c[P1_EPT];
#pragma unroll
  for (int i = 0; i < P1_EPT; ++i) {
    long e = base + (long)i * P1_TPB + tid;
    if (e < E) {
      r[i] = rows[e];
      c[i] = cols[e];
    } else {
      r[i] = -1;
      c[i] = -1;  // r==c -> skipped
    }
  }
  if (tid < nb) hist[tid] = 0;
  __syncthreads();
#pragma unroll
  for (int i = 0; i < P1_EPT; ++i)
    if (r[i] != c[i]) atomicAdd(&hist[r[i] >> RPB_SHIFT], 1);
  __syncthreads();
  if (tid < nb) {
    int h = hist[tid];
    goff[tid] = h ? atomicAdd(&bcur[tid], h) : 0;
    hist[tid] = 0;  // reuse as local rank cursor
  }
  __syncthreads();
#pragma unroll
  for (int i = 0; i < P1_EPT; ++i) {
    if (r[i] != c[i]) {
      int b = r[i] >> RPB_SHIFT;
      int rank = atomicAdd(&hist[b], 1);
      pairs[goff[b] + rank] = ((r[i] & (RPB - 1)) << CBITS) | c[i];
    }
  }
}

// Sort pass 2 + degree/norm/scan fusion: one block per bucket.
// Bucket b's edges live in pairs[b*BCAP .. bcur[b]).
// (1) LDS histogram of local rows -> deg, dis, selfn
// (2) local 1024-wide scan -> row_start (within the bucket's fixed window)
// (3) LDS-cursor scatter -> colidx (writes confined to this bucket's window)
__global__ __launch_bounds__(P1_TPB) void k_part3(const int* __restrict__ bcur,
                                                  const int* __restrict__ pairs,
                                                  int* __restrict__ colidx,
                                                  int* __restrict__ row_start,
                                                  int* __restrict__ deg,
                                                  float* __restrict__ dis,
                                                  float* __restrict__ selfn, int n) {
  __shared__ int lh[RPB];
  __shared__ int lscan[RPB];
  int tid = threadIdx.x;
  int b = blockIdx.x;
  int base = b * RPB;
  int e0 = b * BCAP;
  int e1 = bcur[b];
  lh[tid] = 0;
  __syncthreads();
  for (int i = e0 + tid; i < e1; i += P1_TPB)
    atomicAdd(&lh[pairs[i] >> CBITS], 1);
  __syncthreads();
  int d = lh[tid];
  int row = base + tid;
  if (row < n) {
    float dd = (float)d + 1.0f;
    dis[row] = rsqrtf(dd);
    selfn[row] = 1.0f / dd;
    deg[row] = d;
  }
  // inclusive scan of d
  lscan[tid] = d;
  __syncthreads();
  for (int off = 1; off < RPB; off <<= 1) {
    int t = (tid >= off) ? lscan[tid - off] : 0;
    __syncthreads();
    lscan[tid] += t;
    __syncthreads();
  }
  int rstart = e0 + lscan[tid] - d;  // exclusive, within bucket window
  if (row < n) row_start[row] = rstart;
  lh[tid] = rstart;  // cursor
  __syncthreads();
  for (int i = e0 + tid; i < e1; i += P1_TPB) {
    int v = pairs[i];
    int p = atomicAdd(&lh[v >> CBITS], 1);
    colidx[p] = v & CMASK;
  }
}

// g = dis * (x @ W) stored fp16.
// x tile (32x128 f32 = 16KB) staged in LDS via lane-distributed coalesced
// float4 loads; inner loop reads x as LDS b128 broadcasts, W in registers.
#define GR 32  // rows per block
__global__ __launch_bounds__(256) void k_gemm_scale(const float* __restrict__ x,
                                                    const float* __restrict__ W,
                                                    const float* __restrict__ dis,
                                                    __half* __restrict__ g, int n) {
  __shared__ __align__(16) float xs[GR * 128];  // 16 KB
  int tid = threadIdx.x;
  int f = tid & 63;
  int wid = tid >> 6;
  int row0 = blockIdx.x * GR;
  {
    const float4* xg = (const float4*)(x + (size_t)row0 * 128);
    float4* xs4 = (float4*)xs;
    if (row0 + GR <= n) {
#pragma unroll
      for (int i = 0; i < 4; ++i) xs4[tid + i * 256] = xg[tid + i * 256];
    } else {
      int nf4 = (n - row0) * 32;
      for (int i = tid; i < nf4; i += 256) xs4[i] = xg[i];
    }
  }
  __syncthreads();
  float acc[8] = {0.f, 0.f, 0.f, 0.f, 0.f, 0.f, 0.f, 0.f};
  const float* xw = xs + (wid * 8) * 128;
  for (int kc = 0; kc < 128; kc += 32) {
    float w[32];
#pragma unroll
    for (int j = 0; j < 32; ++j) w[j] = W[(kc + j) * 64 + f];  // coalesced, L2-hit
#pragma unroll
    for (int rr = 0; rr < 8; ++rr) {
      const float* xr = xw + rr * 128 + kc;
#pragma unroll
      for (int j = 0; j < 32; j += 4) {
        float4 xv = *reinterpret_cast<const float4*>(xr + j);  // LDS broadcast
        acc[rr] += xv.x * w[j] + xv.y * w[j + 1] + xv.z * w[j + 2] + xv.w * w[j + 3];
      }
    }
  }
  int rbase = row0 + wid * 8;
#pragma unroll
  for (int rr = 0; rr < 8; ++rr) {
    int row = rbase + rr;
    if (row < n) g[(size_t)row * 64 + f] = __float2half_rn(dis[row] * acc[rr]);
  }
}

// SPMM gather: 2 rows per wave, half2 per lane (features 2*f2, 2*f2+1).
// Per edge: one 128B coalesced half2 load per half-wave. f32 accumulation.
// 8-deep unroll: ~16 independent gather loads in flight per wave (MLP).
template <bool OUTF32>
__global__ __launch_bounds__(256) void k_spmm_h(const int* __restrict__ row_start,
                                                const int* __restrict__ deg,
                                                const int* __restrict__ colidx,
                                                const float* __restrict__ scale,
                                                const __half* __restrict__ gin,
                                                void* __restrict__ gout, int n) {
  int lane = threadIdx.x & 63;
  int wid = threadIdx.x >> 6;
  int r = blockIdx.x * 8 + wid * 2 + (lane >> 5);
  if (r >= n) return;
  int f2 = lane & 31;
  const __half2* gin2 = (const __half2*)gin;
  int start = row_start[r];
  int len = deg[r];
  float2 sv = __half22float2(gin2[(size_t)r * 32 + f2]);  // self loop
  float ax = sv.x, ay = sv.y;
  int j = 0;
  for (; j + 8 <= len; j += 8) {
    int c0 = colidx[start + j + 0];
    int c1 = colidx[start + j + 1];
    int c2 = colidx[start + j + 2];
    int c3 = colidx[start + j + 3];
    int c4 = colidx[start + j + 4];
    int c5 = colidx[start + j + 5];
    int c6 = colidx[start + j + 6];
    int c7 = colidx[start + j + 7];
    float2 v0 = __half22float2(gin2[(size_t)c0 * 32 + f2]);
    float2 v1 = __half22float2(gin2[(size_t)c1 * 32 + f2]);
    float2 v2 = __half22float2(gin2[(size_t)c2 * 32 + f2]);
    float2 v3 = __half22float2(gin2[(size_t)c3 * 32 + f2]);
    float2 v4 = __half22float2(gin2[(size_t)c4 * 32 + f2]);
    float2 v5 = __half22float2(gin2[(size_t)c5 * 32 + f2]);
    float2 v6 = __half22float2(gin2[(size_t)c6 * 32 + f2]);
    float2 v7 = __half22float2(gin2[(size_t)c7 * 32 + f2]);
    ax += (v0.x + v1.x + v2.x + v3.x) + (v4.x + v5.x + v6.x + v7.x);
    ay += (v0.y + v1.y + v2.y + v3.y) + (v4.y + v5.y + v6.y + v7.y);
  }
  for (; j + 4 <= len; j += 4) {
    int c0 = colidx[start + j + 0];
    int c1 = colidx[start + j + 1];
    int c2 = colidx[start + j + 2];
    int c3 = colidx[start + j + 3];
    float2 v0 = __half22float2(gin2[(size_t)c0 * 32 + f2]);
    float2 v1 = __half22float2(gin2[(size_t)c1 * 32 + f2]);
    float2 v2 = __half22float2(gin2[(size_t)c2 * 32 + f2]);
    float2 v3 = __half22float2(gin2[(size_t)c3 * 32 + f2]);
    ax += v0.x + v1.x + v2.x + v3.x;
    ay += v0.y + v1.y + v2.y + v3.y;
  }
  for (; j < len; ++j) {
    int c = colidx[start + j];
    float2 v = __half22float2(gin2[(size_t)c * 32 + f2]);
    ax += v.x;
    ay += v.y;
  }
  float s = scale[r];
  if (OUTF32) {
    ((float2*)gout)[(size_t)r * 32 + f2] = make_float2(s * ax, s * ay);
  } else {
    ((__half2*)gout)[(size_t)r * 32 + f2] = __floats2half2_rn(s * ax, s * ay);
  }
}

extern "C" void kernel_launch(void* const* d_in, const int* in_sizes, int n_in,
                              void* d_out, int out_size, void* d_ws, size_t ws_size,
                              hipStream_t stream) {
  const int* edge = (const int*)d_in[0];
  const float* x = (const float*)d_in[1];
  const float* W = (const float*)d_in[2];
  float* out = (float*)d_out;

  int E = in_sizes[0] / 2;
  int N = in_sizes[1] / 128;
  const int* rows = edge;      // edge_index[0]
  const int* cols = edge + E;  // edge_index[1]
  int nbuckets = (N + RPB - 1) / RPB;  // 98 for N=100000

  char* p = (char*)d_ws;
  auto alloc = [&](size_t bytes) {
    char* q = p;
    p += (bytes + 255) & ~(size_t)255;
    return q;
  };
  size_t slots = (size_t)nbuckets * BCAP;
  int* deg       = (int*)alloc((size_t)N * 4);
  int* row_start = (int*)alloc((size_t)N * 4);
  int* bcur      = (int*)alloc((size_t)nbuckets * 4);
  int* colidx    = (int*)alloc(slots * 4);
  float* dis     = (float*)alloc((size_t)N * 4);
  float* selfn   = (float*)alloc((size_t)N * 4);
  __half* g      = (__half*)alloc((size_t)N * 64 * 2);
  size_t g1_bytes = (size_t)N * 64 * 2;
  size_t pairs_bytes = slots * 4;
  char* g1_raw = (char*)alloc(g1_bytes > pairs_bytes ? g1_bytes : pairs_bytes);
  __half* g1 = (__half*)g1_raw;  // hop-1 output
  int* pairs = (int*)g1_raw;     // aliased: dead before g1 is written

  int p1_blocks = (int)(((long)E + P1_CHUNK - 1) / P1_CHUNK);

  // --- bucketed counting sort (fixed-capacity regions, no pre-count) ---
  k_init_bcur<<<(nbuckets + 127) / 128, 128, 0, stream>>>(bcur, nbuckets);
  k_part1<<<p1_blocks, P1_TPB, 0, stream>>>(rows, cols, bcur, pairs, E, nbuckets);
  k_part3<<<nbuckets, P1_TPB, 0, stream>>>(bcur, pairs, colidx, row_start, deg,
                                           dis, selfn, N);

  // --- feature transform (pre-scaled, fp16 out) ---
  k_gemm_scale<<<(N + GR - 1) / GR, 256, 0, stream>>>(x, W, dis, g, N);

  // --- hop 1: g1 = selfn * (g_self + gather)  [fp16] ---
  k_spmm_h<false><<<(N + 7) / 8, 256, 0, stream>>>(row_start, deg, colidx, selfn,
                                                   g, (void*)g1, N);

  // --- hop 2: out = dis * (g1_self + gather)  [f32] ---
  k_spmm_h<true><<<(N + 7) / 8, 256, 0, stream>>>(row_start, deg, colidx, dis,
                                                  g1, (void*)out, N);
}

// Round 13
// 194.705 us; speedup vs baseline: 2.0148x; 1.1855x over previous
//
#include <hip/hip_runtime.h>
#include <hip/hip_fp16.h>

// GCN 2-hop propagation, CSR-gather formulation, fp16 intermediates.
// GEMM via MFMA f16; sort = fixed-capacity bucketed counting sort.
// Inputs: edge_index (2,E) int32; x (N,128) f32; W (128,64) f32. Output (N,64) f32.
//
// Math: deg[r] = #(non-self edges from r) + 1; dis = rsqrt(deg); selfn = 1/deg.
//   g  = dis * (x@W)                  (stored fp16)
//   g1[r]  = selfn[r] * (g[r]  + sum_{r->c} g[c])    (= dis*y1, stored fp16)
//   out[r] = dis[r]   * (g1[r] + sum_{r->c} g1[c])   (f32)

#define RPB 1024        // rows per bucket
#define RPB_SHIFT 10
#define CBITS 17        // bits for col index (N < 131072)
#define CMASK ((1 << CBITS) - 1)
#define P1_TPB 1024
#define P1_EPT 8
#define P1_CHUNK (P1_TPB * P1_EPT)  // 8192 edges per block
#define MAXNB 128       // max buckets (N <= 131072)
#define BCAP 36864      // bucket capacity; E/nb = 32653, sigma ~180 -> 23 sigma

typedef _Float16 f16x8 __attribute__((ext_vector_type(8)));
typedef float f32x4 __attribute__((ext_vector_type(4)));

// bcur[b] = b*BCAP (start of bucket b's fixed region)
__global__ __launch_bounds__(128) void k_init_bcur(int* __restrict__ bcur, int nb) {
  int b = blockIdx.x * 128 + threadIdx.x;
  if (b < nb) bcur[b] = b * BCAP;
}

// Sort pass 1: 8192 edges/block in registers, LDS histogram over coarse
// buckets, ONE global atomic per (block,bucket), contiguous packed writes.
__global__ __launch_bounds__(P1_TPB) void k_part1(const int* __restrict__ rows,
                                                  const int* __restrict__ cols,
                                                  int* __restrict__ bcur,
                                                  int* __restrict__ pairs,
                                                  int E, int nb) {
  __shared__ int hist[MAXNB];
  __shared__ int goff[MAXNB];
  int tid = threadIdx.x;
  long base = (long)blockIdx.x * P1_CHUNK;
  int r[P1_EPT], c[P1_EPT];
#pragma unroll
  for (int i = 0; i < P1_EPT; ++i) {
    long e = base + (long)i * P1_TPB + tid;
    if (e < E) {
      r[i] = rows[e];
      c[i] = cols[e];
    } else {
      r[i] = -1;
      c[i] = -1;  // r==c -> skipped
    }
  }
  if (tid < nb) hist[tid] = 0;
  __syncthreads();
#pragma unroll
  for (int i = 0; i < P1_EPT; ++i)
    if (r[i] != c[i]) atomicAdd(&hist[r[i] >> RPB_SHIFT], 1);
  __syncthreads();
  if (tid < nb) {
    int h = hist[tid];
    goff[tid] = h ? atomicAdd(&bcur[tid], h) : 0;
    hist[tid] = 0;  // reuse as local rank cursor
  }
  __syncthreads();
#pragma unroll
  for (int i = 0; i < P1_EPT; ++i) {
    if (r[i] != c[i]) {
      int b = r[i] >> RPB_SHIFT;
      int rank = atomicAdd(&hist[b], 1);
      pairs[goff[b] + rank] = ((r[i] & (RPB - 1)) << CBITS) | c[i];
    }
  }
}

// Sort pass 2 + degree/norm/scan fusion: one block per bucket.
__global__ __launch_bounds__(P1_TPB) void k_part3(const int* __restrict__ bcur,
                                                  const int* __restrict__ pairs,
                                                  int* __restrict__ colidx,
                                                  int* __restrict__ row_start,
                                                  int* __restrict__ deg,
                                                  float* __restrict__ dis,
                                                  float* __restrict__ selfn, int n) {
  __shared__ int lh[RPB];
  __shared__ int lscan[RPB];
  int tid = threadIdx.x;
  int b = blockIdx.x;
  int base = b * RPB;
  int e0 = b * BCAP;
  int e1 = bcur[b];
  lh[tid] = 0;
  __syncthreads();
  for (int i = e0 + tid; i < e1; i += P1_TPB)
    atomicAdd(&lh[pairs[i] >> CBITS], 1);
  __syncthreads();
  int d = lh[tid];
  int row = base + tid;
  if (row < n) {
    float dd = (float)d + 1.0f;
    dis[row] = rsqrtf(dd);
    selfn[row] = 1.0f / dd;
    deg[row] = d;
  }
  // inclusive scan of d
  lscan[tid] = d;
  __syncthreads();
  for (int off = 1; off < RPB; off <<= 1) {
    int t = (tid >= off) ? lscan[tid - off] : 0;
    __syncthreads();
    lscan[tid] += t;
    __syncthreads();
  }
  int rstart = e0 + lscan[tid] - d;  // exclusive, within bucket window
  if (row < n) row_start[row] = rstart;
  lh[tid] = rstart;  // cursor
  __syncthreads();
  for (int i = e0 + tid; i < e1; i += P1_TPB) {
    int v = pairs[i];
    int p = atomicAdd(&lh[v >> CBITS], 1);
    colidx[p] = v & CMASK;
  }
}

// g = dis * (x @ W) via mfma_f32_16x16x32_f16, stored fp16.
// Block = 64 rows; 4 waves, each 16 rows x 64 features (16 MFMA).
// x tile + W^T staged fp16 in LDS with +8 row pad (2-way conflicts = free).
// Verified layouts (m89/m97): A/B frag = 8 contiguous k at row lane&15,
// k-base (lane>>4)*8; C/D: col = lane&15, row = (lane>>4)*4 + reg.
#define XPAD 136  // 128 + 8 fp16 pad -> 272B row stride (16B aligned)
__global__ __launch_bounds__(256) void k_gemm_mfma(const float* __restrict__ x,
                                                   const float* __restrict__ W,
                                                   const float* __restrict__ dis,
                                                   __half* __restrict__ g, int n) {
  __shared__ _Float16 xs[64 * XPAD];  // 17.4 KB
  __shared__ _Float16 wt[64 * XPAD];  // W^T: wt[f][k]
  int tid = threadIdx.x;
  int row0 = blockIdx.x * 64;
  // stage W^T (fp16): idx = k*64+f; coalesced read, scattered 2B LDS write
  for (int i = 0; i < 32; ++i) {
    int idx = tid + i * 256;
    int k = idx >> 6, f = idx & 63;
    wt[f * XPAD + k] = (_Float16)W[idx];
  }
  // stage x rows (fp16): thread owns row tid>>2, k-range (tid&3)*32..+32
  {
    int lrow = tid >> 2;
    int kb = (tid & 3) * 32;
    int row = row0 + lrow;
    _Float16* dst = &xs[lrow * XPAD + kb];
    if (row < n) {
      const float* src = x + (size_t)row * 128 + kb;
#pragma unroll
      for (int jj = 0; jj < 4; ++jj) {
        float4 v0 = *(const float4*)(src + jj * 8);
        float4 v1 = *(const float4*)(src + jj * 8 + 4);
        f16x8 t;
        t[0] = (_Float16)v0.x; t[1] = (_Float16)v0.y;
        t[2] = (_Float16)v0.z; t[3] = (_Float16)v0.w;
        t[4] = (_Float16)v1.x; t[5] = (_Float16)v1.y;
        t[6] = (_Float16)v1.z; t[7] = (_Float16)v1.w;
        *(f16x8*)(dst + jj * 8) = t;
      }
    } else {
      f16x8 z = {};
#pragma unroll
      for (int jj = 0; jj < 4; ++jj) *(f16x8*)(dst + jj * 8) = z;
    }
  }
  __syncthreads();
  int wid = tid >> 6, lane = tid & 63;
  int lr = lane & 15;          // A-row / B-col within tile
  int lk = (lane >> 4) * 8;    // k-base within 32
  f32x4 acc[4] = {{0.f, 0.f, 0.f, 0.f}, {0.f, 0.f, 0.f, 0.f},
                  {0.f, 0.f, 0.f, 0.f}, {0.f, 0.f, 0.f, 0.f}};
  const _Float16* xbase = &xs[(wid * 16 + lr) * XPAD + lk];
  const _Float16* wbase = &wt[lr * XPAD + lk];
#pragma unroll
  for (int ks = 0; ks < 4; ++ks) {
    f16x8 a = *(const f16x8*)(xbase + ks * 32);
#pragma unroll
    for (int ft = 0; ft < 4; ++ft) {
      f16x8 b = *(const f16x8*)(wbase + (size_t)ft * 16 * XPAD + ks * 32);
      acc[ft] = __builtin_amdgcn_mfma_f32_16x16x32_f16(a, b, acc[ft], 0, 0, 0);
    }
  }
  int mrow = row0 + wid * 16 + (lane >> 4) * 4;
#pragma unroll
  for (int j = 0; j < 4; ++j) {
    int row = mrow + j;
    if (row < n) {
      float dsc = dis[row];
#pragma unroll
      for (int ft = 0; ft < 4; ++ft)
        g[(size_t)row * 64 + ft * 16 + lr] = __float2half_rn(dsc * acc[ft][j]);
    }
  }
}

// SPMM gather: 2 rows per wave, half2 per lane (features 2*f2, 2*f2+1).
// 16-deep unroll: ~32 independent gather loads in flight per wave (MLP).
template <bool OUTF32>
__global__ __launch_bounds__(256) void k_spmm_h(const int* __restrict__ row_start,
                                                const int* __restrict__ deg,
                                                const int* __restrict__ colidx,
                                                const float* __restrict__ scale,
                                                const __half* __restrict__ gin,
                                                void* __restrict__ gout, int n) {
  int lane = threadIdx.x & 63;
  int wid = threadIdx.x >> 6;
  int r = blockIdx.x * 8 + wid * 2 + (lane >> 5);
  if (r >= n) return;
  int f2 = lane & 31;
  const __half2* gin2 = (const __half2*)gin;
  int start = row_start[r];
  int len = deg[r];
  float2 sv = __half22float2(gin2[(size_t)r * 32 + f2]);  // self loop
  float ax = sv.x, ay = sv.y;
  int j = 0;
  for (; j + 16 <= len; j += 16) {
    int c[16];
#pragma unroll
    for (int u = 0; u < 16; ++u) c[u] = colidx[start + j + u];
    float2 v[16];
#pragma unroll
    for (int u = 0; u < 16; ++u) v[u] = __half22float2(gin2[(size_t)c[u] * 32 + f2]);
#pragma unroll
    for (int u = 0; u < 16; ++u) {
      ax += v[u].x;
      ay += v[u].y;
    }
  }
  for (; j + 4 <= len; j += 4) {
    int c0 = colidx[start + j + 0];
    int c1 = colidx[start + j + 1];
    int c2 = colidx[start + j + 2];
    int c3 = colidx[start + j + 3];
    float2 v0 = __half22float2(gin2[(size_t)c0 * 32 + f2]);
    float2 v1 = __half22float2(gin2[(size_t)c1 * 32 + f2]);
    float2 v2 = __half22float2(gin2[(size_t)c2 * 32 + f2]);
    float2 v3 = __half22float2(gin2[(size_t)c3 * 32 + f2]);
    ax += v0.x + v1.x + v2.x + v3.x;
    ay += v0.y + v1.y + v2.y + v3.y;
  }
  for (; j < len; ++j) {
    int c = colidx[start + j];
    float2 v = __half22float2(gin2[(size_t)c * 32 + f2]);
    ax += v.x;
    ay += v.y;
  }
  float s = scale[r];
  if (OUTF32) {
    ((float2*)gout)[(size_t)r * 32 + f2] = make_float2(s * ax, s * ay);
  } else {
    ((__half2*)gout)[(size_t)r * 32 + f2] = __floats2half2_rn(s * ax, s * ay);
  }
}

extern "C" void kernel_launch(void* const* d_in, const int* in_sizes, int n_in,
                              void* d_out, int out_size, void* d_ws, size_t ws_size,
                              hipStream_t stream) {
  const int* edge = (const int*)d_in[0];
  const float* x = (const float*)d_in[1];
  const float* W = (const float*)d_in[2];
  float* out = (float*)d_out;

  int E = in_sizes[0] / 2;
  int N = in_sizes[1] / 128;
  const int* rows = edge;      // edge_index[0]
  const int* cols = edge + E;  // edge_index[1]
  int nbuckets = (N + RPB - 1) / RPB;  // 98 for N=100000

  char* p = (char*)d_ws;
  auto alloc = [&](size_t bytes) {
    char* q = p;
    p += (bytes + 255) & ~(size_t)255;
    return q;
  };
  size_t slots = (size_t)nbuckets * BCAP;
  int* deg       = (int*)alloc((size_t)N * 4);
  int* row_start = (int*)alloc((size_t)N * 4);
  int* bcur      = (int*)alloc((size_t)nbuckets * 4);
  int* colidx    = (int*)alloc(slots * 4);
  float* dis     = (float*)alloc((size_t)N * 4);
  float* selfn   = (float*)alloc((size_t)N * 4);
  __half* g      = (__half*)alloc((size_t)N * 64 * 2);
  size_t g1_bytes = (size_t)N * 64 * 2;
  size_t pairs_bytes = slots * 4;
  char* g1_raw = (char*)alloc(g1_bytes > pairs_bytes ? g1_bytes : pairs_bytes);
  __half* g1 = (__half*)g1_raw;  // hop-1 output
  int* pairs = (int*)g1_raw;     // aliased: dead before g1 is written

  int p1_blocks = (int)(((long)E + P1_CHUNK - 1) / P1_CHUNK);

  // --- bucketed counting sort (fixed-capacity regions, no pre-count) ---
  k_init_bcur<<<(nbuckets + 127) / 128, 128, 0, stream>>>(bcur, nbuckets);
  k_part1<<<p1_blocks, P1_TPB, 0, stream>>>(rows, cols, bcur, pairs, E, nbuckets);
  k_part3<<<nbuckets, P1_TPB, 0, stream>>>(bcur, pairs, colidx, row_start, deg,
                                           dis, selfn, N);

  // --- feature transform via MFMA (pre-scaled, fp16 out) ---
  k_gemm_mfma<<<(N + 63) / 64, 256, 0, stream>>>(x, W, dis, g, N);

  // --- hop 1: g1 = selfn * (g_self + gather)  [fp16] ---
  k_spmm_h<false><<<(N + 7) / 8, 256, 0, stream>>>(row_start, deg, colidx, selfn,
                                                   g, (void*)g1, N);

  // --- hop 2: out = dis * (g1_self + gather)  [f32] ---
  k_spmm_h<true><<<(N + 7) / 8, 256, 0, stream>>>(row_start, deg, colidx, dis,
                                                  g1, (void*)out, N);
}